// Round 1
// baseline (432.924 us; speedup 1.0000x reference)
//
#include <hip/hip_runtime.h>

typedef __attribute__((ext_vector_type(8))) short short8;
typedef __attribute__((ext_vector_type(8))) unsigned short ushort8;
typedef __attribute__((ext_vector_type(4))) float f32x4;
typedef unsigned short ushort;
typedef unsigned int uint;

// round-to-nearest-even f32 -> bf16 bits
__device__ __forceinline__ ushort f2bf(float f) {
    uint x = __float_as_uint(f);
    x += 0x7fffu + ((x >> 16) & 1u);
    return (ushort)(x >> 16);
}

// -------- kernel 1: q_ws[b][o] = dot(query[b,:512], Wq[o,:512]) + bq[o] + be[o]
__global__ __launch_bounds__(256) void prep_q(
    const float* __restrict__ query, const float* __restrict__ Wq,
    const float* __restrict__ bq, const float* __restrict__ be,
    float* __restrict__ q_ws) {
    __shared__ float qrow[512];
    const int b = blockIdx.x, t = threadIdx.x;
    qrow[t]       = query[b * 512 + t];
    qrow[t + 256] = query[b * 512 + 256 + t];
    __syncthreads();
    const f32x4* wr = (const f32x4*)(Wq + (size_t)t * 512);
    float s = 0.f;
#pragma unroll 8
    for (int j = 0; j < 128; ++j) {
        f32x4 w = wr[j];
        f32x4 q = *(const f32x4*)(qrow + 4 * j);   // LDS broadcast, no conflict
        s += w.x * q.x + w.y * q.y + w.z * q.z + w.w * q.w;
    }
    q_ws[b * 256 + t] = s + bq[t] + be[t];
}

// -------- kernel 2: Web[o][h] = bf16(We[o][h])   (65536 elements)
__global__ __launch_bounds__(256) void conv_we(
    const float* __restrict__ We, ushort* __restrict__ Web) {
    const int i = (blockIdx.x * 256 + threadIdx.x) * 4;
    float4 v = *(const float4*)(We + i);
    ushort4 u;
    u.x = f2bf(v.x); u.y = f2bf(v.y); u.z = f2bf(v.z); u.w = f2bf(v.w);
    *(ushort4*)(Web + i) = u;
}

// -------- kernel 3: fused GEMM (e = ref@We^T) + tanh-scorer reduction
// M = 262144 rows, N = 256, K = 256.  Block: 256 thr (4 waves), M-tile 64.
#define BM 64
#define BK 32
#define LDA 40   // padded LDS stride (bf16 elems): 2-way bank aliasing only
#define LDB 40

__global__ __launch_bounds__(256) void fused_gemm(
    const float* __restrict__ ref, const ushort* __restrict__ Web,
    const float* __restrict__ q_ws, const float* __restrict__ Wv,
    const float* __restrict__ bv, float* __restrict__ out) {
    __shared__ ushort Asm[BM * LDA];      // 5120 B
    __shared__ ushort Bsm[256 * LDB];     // 20480 B
    __shared__ float red[4][64];

    const int t = threadIdx.x;
    const int w = t >> 6;          // wave 0..3 -> col strip [64w, 64w+64)
    const int l = t & 63;
    const int quad = l >> 4;       // 0..3
    const int lr = l & 15;
    const size_t row0 = (size_t)blockIdx.x * BM;
    const int b = (int)(row0 >> 10);           // 64 | 1024 -> constant per block

    f32x4 acc[4][4];
#pragma unroll
    for (int i = 0; i < 4; ++i)
#pragma unroll
        for (int j = 0; j < 4; ++j) acc[i][j] = (f32x4){0.f, 0.f, 0.f, 0.f};

    // staging roles
    const int ar = t >> 2;               // A row 0..63 (4 thr/row)
    const int ac = (t & 3) * 8;          // 8 f32 each
    const float* aptr = ref + (row0 + ar) * 256 + ac;
    ushort* asd = Asm + ar * LDA + ac;

    const int br = t >> 2;               // B rows {br, br+64, br+128, br+192}
    const int bc = (t & 3) * 8;

    for (int kk = 0; kk < 8; ++kk) {
        // ---- stage A: f32 global -> bf16 LDS
        float4 a0 = *(const float4*)(aptr + kk * 32);
        float4 a1 = *(const float4*)(aptr + kk * 32 + 4);
        ushort8 av;
        av[0] = f2bf(a0.x); av[1] = f2bf(a0.y); av[2] = f2bf(a0.z); av[3] = f2bf(a0.w);
        av[4] = f2bf(a1.x); av[5] = f2bf(a1.y); av[6] = f2bf(a1.z); av[7] = f2bf(a1.w);
        *(ushort8*)asd = av;
        // ---- stage B: bf16 global (L2-resident) -> LDS
#pragma unroll
        for (int i = 0; i < 4; ++i) {
            const int n = br + i * 64;
            *(ushort8*)(Bsm + n * LDB + bc) =
                *(const ushort8*)(Web + n * 256 + kk * 32 + bc);
        }
        __syncthreads();

        // ---- fragments + MFMA
        short8 af[4], bf[4];
        const ushort* Ab = Asm + lr * LDA + quad * 8;
        const ushort* Bb = Bsm + (w * 64 + lr) * LDB + quad * 8;
#pragma unroll
        for (int rb = 0; rb < 4; ++rb) af[rb] = *(const short8*)(Ab + rb * 16 * LDA);
#pragma unroll
        for (int cb = 0; cb < 4; ++cb) bf[cb] = *(const short8*)(Bb + cb * 16 * LDB);
#pragma unroll
        for (int rb = 0; rb < 4; ++rb)
#pragma unroll
            for (int cb = 0; cb < 4; ++cb)
                acc[rb][cb] = __builtin_amdgcn_mfma_f32_16x16x32_bf16(
                    af[rb], bf[cb], acc[rb][cb], 0, 0, 0);
        __syncthreads();
    }

    // ---- epilogue: out[row] = sum_n tanh(q[b,n] + e[row,n]) * Wv[n&31] + 8*bv
    const float* qe = q_ws + b * 256;
    const float wv0 = Wv[lr];
    const float wv1 = Wv[16 + lr];
    float qv[4];
#pragma unroll
    for (int cb = 0; cb < 4; ++cb) qv[cb] = qe[w * 64 + cb * 16 + lr];

    float part[4][4];
#pragma unroll
    for (int rb = 0; rb < 4; ++rb)
#pragma unroll
        for (int r = 0; r < 4; ++r) part[rb][r] = 0.f;

#pragma unroll
    for (int cb = 0; cb < 4; ++cb) {
        const float wvv = (cb & 1) ? wv1 : wv0;   // (n & 31) = 16*(cb&1) + lr
#pragma unroll
        for (int rb = 0; rb < 4; ++rb)
#pragma unroll
            for (int r = 0; r < 4; ++r) {
                float x = acc[rb][cb][r] + qv[cb];
                float th = 1.f - 2.f / (__expf(2.f * x) + 1.f);
                part[rb][r] += th * wvv;
            }
    }
    // reduce across the 16 column-lanes (xor bits 0..3)
#pragma unroll
    for (int off = 1; off < 16; off <<= 1)
#pragma unroll
        for (int rb = 0; rb < 4; ++rb)
#pragma unroll
            for (int r = 0; r < 4; ++r)
                part[rb][r] += __shfl_xor(part[rb][r], off, 64);

    if (lr == 0) {
#pragma unroll
        for (int rb = 0; rb < 4; ++rb)
#pragma unroll
            for (int r = 0; r < 4; ++r)
                red[w][rb * 16 + quad * 4 + r] = part[rb][r];
    }
    __syncthreads();
    if (t < 64) {
        float s = red[0][t] + red[1][t] + red[2][t] + red[3][t] + 8.f * bv[0];
        out[row0 + t] = s;
    }
}

extern "C" void kernel_launch(void* const* d_in, const int* in_sizes, int n_in,
                              void* d_out, int out_size, void* d_ws, size_t ws_size,
                              hipStream_t stream) {
    const float* query = (const float*)d_in[0];
    const float* ref   = (const float*)d_in[1];
    const float* Wq    = (const float*)d_in[2];
    const float* bq    = (const float*)d_in[3];
    const float* We    = (const float*)d_in[4];
    const float* be    = (const float*)d_in[5];
    const float* Wv    = (const float*)d_in[6];
    const float* bv    = (const float*)d_in[7];
    float* out = (float*)d_out;

    float*  q_ws = (float*)d_ws;                                   // 256 KB
    ushort* Web  = (ushort*)((char*)d_ws + 65536 * sizeof(float)); // 128 KB

    prep_q<<<256, 256, 0, stream>>>(query, Wq, bq, be, q_ws);
    conv_we<<<64, 256, 0, stream>>>(We, Web);
    fused_gemm<<<4096, 256, 0, stream>>>(ref, Web, q_ws, Wv, bv, out);
}